// Round 14
// baseline (2292.614 us; speedup 1.0000x reference)
//
#include <hip/hip_runtime.h>
#include <cstdint>
#include <cstddef>

#define BATCH 4096
#define DIM 64
#define HID 512
#define NPER 2048
#define KEV 25
#define DT_C 0.01f
#define LOG_SQRT_2PI_C 0.9189385332046727f

typedef __attribute__((ext_vector_type(8))) short short8;
typedef __attribute__((ext_vector_type(4))) float f32x4;

#define MFMA(a, b, c) __builtin_amdgcn_mfma_f32_16x16x32_bf16(a, b, c, 0, 0, 0)
#define BARRIER() __builtin_amdgcn_s_barrier()
#define SCHED0()  __builtin_amdgcn_sched_barrier(0)

__device__ __forceinline__ ushort f2bf(float f) {
    uint32_t u = __float_as_uint(f);
    u += 0x7FFF + ((u >> 16) & 1);
    return (ushort)(u >> 16);
}
__device__ __forceinline__ float sigmoidf_(float x) { return 1.0f / (1.0f + expf(-x)); }

__device__ __forceinline__ void gload_lds16(const ushort* g, ushort* l) {
    __builtin_amdgcn_global_load_lds(
        (const __attribute__((address_space(1))) void*)g,
        (__attribute__((address_space(3))) void*)l, 16, 0, 0);
}
__device__ __forceinline__ void wait_vm(int n) {
    if (n == 8)      asm volatile("s_waitcnt vmcnt(8)" ::: "memory");
    else if (n == 6) asm volatile("s_waitcnt vmcnt(6)" ::: "memory");
    else if (n == 4) asm volatile("s_waitcnt vmcnt(4)" ::: "memory");
    else             asm volatile("s_waitcnt vmcnt(0)" ::: "memory");
}

// fragment from [rows][64] LDS tile, XOR-swizzled 8-elem slots (BK=64 bodies)
__device__ __forceinline__ short8 frag64(const ushort* lds, int row, int ks, int lane) {
    int slot = ((ks << 2) + (lane >> 4)) ^ (row & 7);
    return *(const short8*)&lds[row * 64 + slot * 8];
}
// fragment from [64][128] LDS tile (BK=128 bodies)
__device__ __forceinline__ short8 frag128(const ushort* lds, int row, int ks, int lane) {
    int slot = ((ks << 2) + (lane >> 4)) ^ (row & 7);
    return *(const short8*)&lds[row * 128 + slot * 8];
}
// B fragment direct from global (row-major, leading dim ldb)
__device__ __forceinline__ short8 bglob(const ushort* B, int col, int ldb, int k0, int ks, int lane) {
    int slot = (ks << 2) + (lane >> 4);
    return *(const short8*)&B[(size_t)col * ldb + k0 + slot * 8];
}

// stage one 64x128 panel (4 gloads/wave, 4 rows each), pre-swizzled source
__device__ __forceinline__ void stage128(
    const ushort* g, int row0, int k0, int w, int lane, ushort* lds)
{
    #pragma unroll
    for (int gg = 0; gg < 4; ++gg) {
        int row = row0 + w * 16 + gg * 4 + (lane >> 4);
        int slot = (lane & 15) ^ (row & 7);
        gload_lds16(g + (size_t)row * HID + k0 + slot * 8,
                    &lds[(w * 16 + gg * 4) * 128]);
    }
}

// ---- 64x64 tile, K=512 via 4 x BK=128 panels, depth-2 counted-vmcnt --------
__device__ __forceinline__ void gemm_bk128(
    ushort* A0, ushort* A1, ushort* B0, ushort* B1,
    int w, int lane, int wr, int wc,
    const ushort* Ag, int arow0, const ushort* Bg, int brow0,
    f32x4 acc[2][2])
{
    stage128(Ag, arow0, 0, w, lane, A0);
    stage128(Bg, brow0, 0, w, lane, B0);
    stage128(Ag, arow0, 128, w, lane, A1);
    stage128(Bg, brow0, 128, w, lane, B1);
    for (int t = 0; t < 4; ++t) {
        wait_vm((t < 3) ? 8 : 0);
        BARRIER();
        SCHED0();
        const ushort* Ab = (t & 1) ? A1 : A0;
        const ushort* Bb = (t & 1) ? B1 : B0;
        short8 af[2][4], bf[2][4];
        #pragma unroll
        for (int mi = 0; mi < 2; ++mi) {
            int r = wr * 32 + mi * 16 + (lane & 15);
            #pragma unroll
            for (int ks = 0; ks < 4; ++ks) af[mi][ks] = frag128(Ab, r, ks, lane);
        }
        #pragma unroll
        for (int ni = 0; ni < 2; ++ni) {
            int c = wc * 32 + ni * 16 + (lane & 15);
            #pragma unroll
            for (int ks = 0; ks < 4; ++ks) bf[ni][ks] = frag128(Bb, c, ks, lane);
        }
        #pragma unroll
        for (int ks = 0; ks < 4; ++ks)
            #pragma unroll
            for (int mi = 0; mi < 2; ++mi)
                #pragma unroll
                for (int ni = 0; ni < 2; ++ni)
                    acc[mi][ni] = MFMA(af[mi][ks], bf[ni][ks], acc[mi][ni]);
        SCHED0();
        BARRIER();
        if (t + 2 < 4) {
            stage128(Ag, arow0, (t + 2) * 128, w, lane, (t & 1) ? A1 : A0);
            stage128(Bg, brow0, (t + 2) * 128, w, lane, (t & 1) ? B1 : B0);
        }
    }
}

// ---------------- fuse1: ODE-A (bid<512) + q-head of prev event -------------
// mode 0: ode only (512); mode 1: ode + q (768); mode 2: q only (256)
__global__ __launch_bounds__(256) void fuse1(
    const ushort* __restrict__ hb, const ushort* __restrict__ W1,
    const float* __restrict__ b1, ushort* __restrict__ tbb,
    const ushort* __restrict__ hgb, const ushort* __restrict__ Wp1,
    const float* __restrict__ bp1, ushort* __restrict__ qb, int mode)
{
    __shared__ __align__(16) ushort smem[32768];
    ushort* A0 = smem;         ushort* A1 = smem + 8192;
    ushort* B0 = smem + 16384; ushort* B1 = smem + 24576;
    const int tid = threadIdx.x, lane = tid & 63, w = tid >> 6;
    const int wr = w >> 1, wc = w & 1;
    const int bid = blockIdx.x;

    bool isQ; int b;
    if (mode == 2)      { isQ = true;  b = bid; }
    else if (bid < 512) { isQ = false; b = bid; }
    else                { isQ = true;  b = bid - 512; }
    const ushort* A = isQ ? hgb : hb;
    const ushort* W = isQ ? Wp1 : W1;
    const float* bias = isQ ? bp1 : b1;
    const int r0 = (b >> 3) * 64, c0 = (b & 7) * 64;

    f32x4 acc[2][2] = {};
    gemm_bk128(A0, A1, B0, B1, w, lane, wr, wc, A, r0, W, c0, acc);

    #pragma unroll
    for (int mi = 0; mi < 2; ++mi)
        #pragma unroll
        for (int ni = 0; ni < 2; ++ni) {
            const int c = c0 + wc * 32 + ni * 16 + (lane & 15);
            const float bv = bias[c];
            #pragma unroll
            for (int ii = 0; ii < 4; ++ii) {
                const int r = r0 + wr * 32 + mi * 16 + ((lane >> 4) << 2) + ii;
                const size_t o = (size_t)r * HID + c;
                float v = acc[mi][ni][ii] + bv;
                if (!isQ) tbb[o] = f2bf(tanhf(v));
                else      qb[o]  = f2bf(fmaxf(v, 0.0f));
            }
        }
}

// ---------------- fuse2: ODE-B (bid<512) + p_loss of prev event -------------
// inv != nullptr -> also write hgb snapshot via inverse index (step 2 only)
// mode 0: ode only (512); mode 1: ode + p_loss (544); mode 2: p_loss only (32)
__global__ __launch_bounds__(256) void fuse2(
    const ushort* __restrict__ tbb, const ushort* __restrict__ W2,
    const float* __restrict__ b2, float* __restrict__ h, ushort* __restrict__ hb,
    const int* __restrict__ inv, ushort* __restrict__ hgb,
    const ushort* __restrict__ qb, const ushort* __restrict__ Wp2,
    const float* __restrict__ bp2, const float* __restrict__ Xp,
    const float* __restrict__ Mp, float* __restrict__ sums, int mode)
{
    __shared__ __align__(16) ushort smem[32768];
    const int tid = threadIdx.x, lane = tid & 63, w = tid >> 6;
    const int wr = w >> 1, wc = w & 1;
    const int bid = blockIdx.x;

    bool isP; int b;
    if (mode == 2)      { isP = true;  b = bid; }
    else if (bid < 512) { isP = false; b = bid; }
    else                { isP = true;  b = bid - 512; }

    if (!isP) {
        ushort* A0 = smem;         ushort* A1 = smem + 8192;
        ushort* B0 = smem + 16384; ushort* B1 = smem + 24576;
        const int r0 = (b >> 3) * 64, c0 = (b & 7) * 64;
        f32x4 acc[2][2] = {};
        gemm_bk128(A0, A1, B0, B1, w, lane, wr, wc, tbb, r0, W2, c0, acc);
        #pragma unroll
        for (int mi = 0; mi < 2; ++mi)
            #pragma unroll
            for (int ni = 0; ni < 2; ++ni) {
                const int c = c0 + wc * 32 + ni * 16 + (lane & 15);
                const float bv = b2[c];
                #pragma unroll
                for (int ii = 0; ii < 4; ++ii) {
                    const int r = r0 + wr * 32 + mi * 16 + ((lane >> 4) << 2) + ii;
                    const size_t o = (size_t)r * HID + c;
                    float nh = h[o] + DT_C * (acc[mi][ni][ii] + bv);
                    h[o] = nh;
                    ushort bv16 = f2bf(nh);
                    hb[o] = bv16;
                    if (inv) {
                        int iv = inv[r];
                        if (iv >= 0) hgb[(size_t)iv * HID + c] = bv16;
                    }
                }
            }
        return;
    }

    // ---- p_loss: p = q Wp2^T + bp2, fused NLL reduce (BK=64 body) ----
    ushort* A0 = smem;        ushort* A1 = smem + 4096;
    ushort* B0 = smem + 8192; ushort* B1 = smem + 16384;   // 128x64 each
    const int srow = lane >> 3, sg = ((lane & 7) ^ srow) << 3;
    const int r0t = b * 64;
    const int arow = w * 16 + srow;

    auto stage = [&](int bb, int k0) {
        ushort* A = bb ? A1 : A0; ushort* B = bb ? B1 : B0;
        gload_lds16(qb + (size_t)(r0t + arow) * HID + k0 + sg, &A[(w * 16) * 64]);
        gload_lds16(qb + (size_t)(r0t + arow + 8) * HID + k0 + sg, &A[(w * 16 + 8) * 64]);
        #pragma unroll
        for (int j = 0; j < 4; ++j) {
            int g = w * 4 + j;
            int rw = g * 8 + srow;
            gload_lds16(Wp2 + (size_t)rw * HID + k0 + (((lane & 7) ^ (rw & 7)) << 3),
                        &B[g * 8 * 64]);
        }
    };
    f32x4 acc[2][4] = {};
    stage(0, 0);
    stage(1, 64);
    for (int t = 0; t < 8; ++t) {
        wait_vm((t < 7) ? 6 : 0);
        BARRIER();
        SCHED0();
        const ushort* Ab = (t & 1) ? A1 : A0;
        const ushort* Bb = (t & 1) ? B1 : B0;
        short8 af[2][2], bf[4][2];
        #pragma unroll
        for (int mi = 0; mi < 2; ++mi) {
            int r = wr * 32 + mi * 16 + (lane & 15);
            af[mi][0] = frag64(Ab, r, 0, lane);
            af[mi][1] = frag64(Ab, r, 1, lane);
        }
        #pragma unroll
        for (int ni = 0; ni < 4; ++ni) {
            int c = wc * 64 + ni * 16 + (lane & 15);
            bf[ni][0] = frag64(Bb, c, 0, lane);
            bf[ni][1] = frag64(Bb, c, 1, lane);
        }
        #pragma unroll
        for (int ks = 0; ks < 2; ++ks)
            #pragma unroll
            for (int mi = 0; mi < 2; ++mi)
                #pragma unroll
                for (int ni = 0; ni < 4; ++ni)
                    acc[mi][ni] = MFMA(af[mi][ks], bf[ni][ks], acc[mi][ni]);
        SCHED0();
        BARRIER();
        if (t + 2 < 8) stage(t & 1, (t + 2) * 64);
    }

    float* Plds = (float*)smem;   // 64x128 f32 = 32KB
    #pragma unroll
    for (int mi = 0; mi < 2; ++mi)
        #pragma unroll
        for (int ni = 0; ni < 4; ++ni) {
            int c = wc * 64 + ni * 16 + (lane & 15);
            float bv = bp2[c];
            #pragma unroll
            for (int ii = 0; ii < 4; ++ii) {
                int r = wr * 32 + mi * 16 + ((lane >> 4) << 2) + ii;
                Plds[r * 128 + c] = acc[mi][ni][ii] + bv;
            }
        }
    __syncthreads();

    float local = 0.0f;
    for (int t = tid; t < 64 * 64; t += 256) {
        int r = t >> 6, jj = t & 63;
        float mean = Plds[r * 128 + jj];
        float lv   = Plds[r * 128 + 64 + jj];
        int g = r0t + r;
        float err = (Xp[(size_t)g * 64 + jj] - mean) * expf(-0.5f * lv);
        local += 0.5f * (err * err + lv + 2.0f * LOG_SQRT_2PI_C) * Mp[(size_t)g * 64 + jj];
    }
    #pragma unroll
    for (int o = 32; o > 0; o >>= 1) local += __shfl_down(local, o);
    if (lane == 0) atomicAdd(sums, local);
}

// ---------------- gru_all: 1024 blocks = 128 row-tiles(16) x 8 col-tiles ----
// B in registers (6 short8/wave, depth-2 prefetch); A via 1-2 gload_lds/panel.
__global__ __launch_bounds__(256) void gru_all(
    const ushort* __restrict__ hgb, const ushort* __restrict__ Xbk,
    const int* __restrict__ idx,
    const ushort* __restrict__ Whh, const ushort* __restrict__ Wih,
    const float* __restrict__ bih, const float* __restrict__ bhh,
    float* __restrict__ h, ushort* __restrict__ hb)
{
    __shared__ __align__(16) ushort Asm[2][16 * 64];   // 2KB each
    const int tid = threadIdx.x, lane = tid & 63, w = tid >> 6;
    const int srow = lane >> 3, sg = ((lane & 7) ^ srow) << 3;
    const int bid = blockIdx.x;
    const int r0t = (bid >> 3) * 16, c0 = (bid & 7) * 64;
    const int cB = c0 + w * 16 + (lane & 15);

    // waves 0,1 stage 8 A-rows each
    auto stageA = [&](int b, int p) {
        if (w < 2) {
            const ushort* src = (p < 8)
                ? hgb + (size_t)(r0t + w * 8 + srow) * HID + p * 64 + sg
                : Xbk + (size_t)(r0t + w * 8 + srow) * DIM + sg;
            gload_lds16(src, &Asm[b][(w * 8) * 64]);
        }
    };
    short8 bcur[3][2], bnxt[3][2];
    auto loadB = [&](short8 d[3][2], int p) {
        #pragma unroll
        for (int g = 0; g < 3; ++g)
            #pragma unroll
            for (int ks = 0; ks < 2; ++ks)
                d[g][ks] = (p < 8)
                    ? bglob(Whh, g * 512 + cB, HID, p * 64, ks, lane)
                    : bglob(Wih, g * 512 + cB, DIM, 0, ks, lane);
    };

    f32x4 aR = {}, aZ = {}, aNh = {}, aNx = {};
    stageA(0, 0);
    loadB(bcur, 0);
    stageA(1, 1);
    __syncthreads();

    #pragma unroll
    for (int t = 0; t < 9; ++t) {
        if (t < 8) loadB(bnxt, t + 1);
        const ushort* Ab = &Asm[t & 1][0];
        short8 af0 = frag64(Ab, lane & 15, 0, lane);
        short8 af1 = frag64(Ab, lane & 15, 1, lane);
        aR = MFMA(af0, bcur[0][0], aR); aR = MFMA(af1, bcur[0][1], aR);
        aZ = MFMA(af0, bcur[1][0], aZ); aZ = MFMA(af1, bcur[1][1], aZ);
        if (t < 8) { aNh = MFMA(af0, bcur[2][0], aNh); aNh = MFMA(af1, bcur[2][1], aNh); }
        else       { aNx = MFMA(af0, bcur[2][0], aNx); aNx = MFMA(af1, bcur[2][1], aNx); }
        if (t < 8) {
            #pragma unroll
            for (int g = 0; g < 3; ++g) {
                bcur[g][0] = bnxt[g][0];
                bcur[g][1] = bnxt[g][1];
            }
            __syncthreads();           // all waves done reading Asm[t&1]
            stageA(t & 1, t + 2);      // issue A panel t+2 into freed buffer
        }
    }

    // ---- epilogue: GRU combine + scatter into h (fp32) and hb ----
    {
        const float bR = bih[cB] + bhh[cB];
        const float bZ = bih[512 + cB] + bhh[512 + cB];
        const float bNx = bih[1024 + cB], bNh = bhh[1024 + cB];
        #pragma unroll
        for (int ii = 0; ii < 4; ++ii) {
            const int iobs = r0t + ((lane >> 4) << 2) + ii;
            const int gr = idx[iobs];
            float r = sigmoidf_(aR[ii] + bR);
            float z = sigmoidf_(aZ[ii] + bZ);
            float n = tanhf(aNx[ii] + bNx + r * (aNh[ii] + bNh));
            const size_t o = (size_t)gr * HID + cB;
            float nh = (1.0f - z) * n + z * h[o];
            h[o] = nh;
            hb[o] = f2bf(nh);
        }
    }
}

__device__ __forceinline__ void block_atomic_sum(float v, float* acc) {
    __shared__ float red[4];
    #pragma unroll
    for (int off = 32; off > 0; off >>= 1) v += __shfl_down(v, off);
    int lane = threadIdx.x & 63, wid = threadIdx.x >> 6;
    if (lane == 0) red[wid] = v;
    __syncthreads();
    if (threadIdx.x == 0) atomicAdd(acc, red[0] + red[1] + red[2] + red[3]);
}

__global__ __launch_bounds__(256) void f2b4_kernel(
    const float* __restrict__ s, ushort* __restrict__ d, int n4)
{
    int t = blockIdx.x * 256 + threadIdx.x;
    if (t >= n4) return;
    float4 v = ((const float4*)s)[t];
    ushort4 o; o.x = f2bf(v.x); o.y = f2bf(v.y); o.z = f2bf(v.z); o.w = f2bf(v.w);
    ((ushort4*)d)[t] = o;
}

__global__ __launch_bounds__(256) void msum_kernel(
    const float* __restrict__ M, int n, float* __restrict__ m_acc)
{
    float v = 0.0f;
    for (int t = blockIdx.x * 256 + threadIdx.x; t < n; t += gridDim.x * 256)
        v += M[t];
    block_atomic_sum(v, m_acc);
}

__global__ __launch_bounds__(256) void inv_scatter(
    const int* __restrict__ bidx, int* __restrict__ inv)
{
    int t = blockIdx.x * 256 + threadIdx.x;   // over KEV*NPER
    if (t >= KEV * NPER) return;
    int e = t >> 11, i = t & (NPER - 1);
    inv[(size_t)e * BATCH + bidx[t]] = i;
}

__global__ void finalize_kernel(const float* __restrict__ sums, float* __restrict__ out) {
    if (threadIdx.x == 0) { out[0] = sums[0] / sums[1]; out[1] = 0.0f; }
}

extern "C" void kernel_launch(void* const* d_in, const int* in_sizes, int n_in,
                              void* d_out, int out_size, void* d_ws, size_t ws_size,
                              hipStream_t stream) {
    const float* X      = (const float*)d_in[3];
    const float* M      = (const float*)d_in[4];
    const int* batch_idx= (const int*)  d_in[5];
    const float* W_ode1 = (const float*)d_in[6];
    const float* b_ode1 = (const float*)d_in[7];
    const float* W_ode2 = (const float*)d_in[8];
    const float* b_ode2 = (const float*)d_in[9];
    const float* W_ih   = (const float*)d_in[10];
    const float* W_hh   = (const float*)d_in[11];
    const float* b_ih   = (const float*)d_in[12];
    const float* b_hh   = (const float*)d_in[13];
    const float* Wp1    = (const float*)d_in[14];
    const float* bp1    = (const float*)d_in[15];
    const float* Wp2    = (const float*)d_in[16];
    const float* bp2    = (const float*)d_in[17];
    float* out = (float*)d_out;

    float* ws    = (float*)d_ws;
    float* h     = ws;                                  // 4096*512
    float* sums  = h + (size_t)BATCH * HID;             // 16
    int*   inv   = (int*)(sums + 16);                   // 25*4096
    ushort* hb   = (ushort*)(inv + (size_t)KEV * BATCH);// 4096*512
    ushort* tbb  = hb  + (size_t)BATCH * HID;           // 4096*512
    ushort* qb   = tbb + (size_t)BATCH * HID;           // 2048*512
    ushort* hgb  = qb  + (size_t)NPER * HID;            // 2048*512
    ushort* Xb   = hgb + (size_t)NPER * HID;            // 25*2048*64
    ushort* W1b  = Xb  + (size_t)KEV * NPER * DIM;      // 512*512
    ushort* W2b  = W1b + (size_t)HID * HID;
    ushort* Wp1b = W2b + (size_t)HID * HID;
    ushort* Wp2b = Wp1b + (size_t)HID * HID;            // 128*512
    ushort* Wihb = Wp2b + (size_t)2 * DIM * HID;        // 1536*64
    ushort* Whhb = Wihb + (size_t)3 * HID * DIM;        // 1536*512

    hipMemsetAsync(h,    0, (size_t)BATCH * HID * sizeof(float), stream);
    hipMemsetAsync(hb,   0, (size_t)BATCH * HID * sizeof(ushort), stream);
    hipMemsetAsync(sums, 0, 2 * sizeof(float), stream);
    hipMemsetAsync(inv,  0xFF, (size_t)KEV * BATCH * sizeof(int), stream);

    dim3 blk(256);
    auto cvt = [&](const float* s, ushort* d, size_t n) {
        f2b4_kernel<<<dim3((unsigned)((n / 4 + 255) / 256)), blk, 0, stream>>>(s, d, (int)(n / 4));
    };
    cvt(W_ode1, W1b,  (size_t)HID * HID);
    cvt(W_ode2, W2b,  (size_t)HID * HID);
    cvt(Wp1,    Wp1b, (size_t)HID * HID);
    cvt(Wp2,    Wp2b, (size_t)2 * DIM * HID);
    cvt(W_ih,   Wihb, (size_t)3 * HID * DIM);
    cvt(W_hh,   Whhb, (size_t)3 * HID * HID);
    cvt(X,      Xb,   (size_t)KEV * NPER * DIM);

    msum_kernel<<<1024, blk, 0, stream>>>(M, KEV * NPER * DIM, sums + 1);
    inv_scatter<<<(KEV * NPER + 255) / 256, blk, 0, stream>>>(batch_idx, inv);

    for (int k = 0; k < KEV; ++k) {
        const ushort* Xbk = Xb + (size_t)k * NPER * DIM;
        const int*   idxk = batch_idx + (size_t)k * NPER;
        int* invk = inv + (size_t)k * BATCH;
        const float* Xp = X + (size_t)(k > 0 ? k - 1 : 0) * NPER * DIM;
        const float* Mp = M + (size_t)(k > 0 ? k - 1 : 0) * NPER * DIM;
        const int m1 = (k > 0) ? 1 : 0;

        // D1: ODE-A step1 (+ q of event k-1)
        fuse1<<<dim3(m1 ? 768 : 512), blk, 0, stream>>>(
            hb, W1b, b_ode1, tbb, hgb, Wp1b, bp1, qb, m1);
        // D2: ODE-B step1 (+ p_loss of event k-1); no snapshot
        fuse2<<<dim3(m1 ? 544 : 512), blk, 0, stream>>>(
            tbb, W2b, b_ode2, h, hb, nullptr, hgb,
            qb, Wp2b, bp2, Xp, Mp, sums, m1);
        // D3: ODE-A step2
        fuse1<<<dim3(512), blk, 0, stream>>>(
            hb, W1b, b_ode1, tbb, hgb, Wp1b, bp1, qb, 0);
        // D4: ODE-B step2 + hgb snapshot via inv
        fuse2<<<dim3(512), blk, 0, stream>>>(
            tbb, W2b, b_ode2, h, hb, invk, hgb,
            qb, Wp2b, bp2, Xp, Mp, sums, 0);
        // D5: GRU fused (B-in-reg, 1024 blocks)
        gru_all<<<dim3(1024), blk, 0, stream>>>(
            hgb, Xbk, idxk, Whhb, Wihb, b_ih, b_hh, h, hb);
    }

    // tail: head of final event
    {
        const float* Xp = X + (size_t)(KEV - 1) * NPER * DIM;
        const float* Mp = M + (size_t)(KEV - 1) * NPER * DIM;
        fuse1<<<dim3(256), blk, 0, stream>>>(
            hb, W1b, b_ode1, tbb, hgb, Wp1b, bp1, qb, 2);
        fuse2<<<dim3(32), blk, 0, stream>>>(
            tbb, W2b, b_ode2, h, hb, nullptr, hgb,
            qb, Wp2b, bp2, Xp, Mp, sums, 2);
    }

    finalize_kernel<<<1, 64, 0, stream>>>(sums, out);
}

// Round 15
// 2147.805 us; speedup vs baseline: 1.0674x; 1.0674x over previous
//
#include <hip/hip_runtime.h>
#include <cstdint>
#include <cstddef>

#define BATCH 4096
#define DIM 64
#define HID 512
#define NPER 2048
#define KEV 25
#define DT_C 0.01f
#define LOG_SQRT_2PI_C 0.9189385332046727f

typedef __attribute__((ext_vector_type(8))) short short8;
typedef __attribute__((ext_vector_type(4))) float f32x4;

#define MFMA(a, b, c) __builtin_amdgcn_mfma_f32_16x16x32_bf16(a, b, c, 0, 0, 0)
#define BARRIER() __builtin_amdgcn_s_barrier()
#define SCHED0()  __builtin_amdgcn_sched_barrier(0)

__device__ __forceinline__ ushort f2bf(float f) {
    uint32_t u = __float_as_uint(f);
    u += 0x7FFF + ((u >> 16) & 1);
    return (ushort)(u >> 16);
}
__device__ __forceinline__ float sigmoidf_(float x) { return 1.0f / (1.0f + expf(-x)); }

__device__ __forceinline__ void gload_lds16(const ushort* g, ushort* l) {
    __builtin_amdgcn_global_load_lds(
        (const __attribute__((address_space(1))) void*)g,
        (__attribute__((address_space(3))) void*)l, 16, 0, 0);
}
__device__ __forceinline__ void wait_vm(int n) {
    if (n == 8)      asm volatile("s_waitcnt vmcnt(8)" ::: "memory");
    else if (n == 6) asm volatile("s_waitcnt vmcnt(6)" ::: "memory");
    else if (n == 4) asm volatile("s_waitcnt vmcnt(4)" ::: "memory");
    else             asm volatile("s_waitcnt vmcnt(0)" ::: "memory");
}

// fragment from [rows][64] LDS tile, XOR-swizzled 8-elem slots (BK=64 bodies)
__device__ __forceinline__ short8 frag64(const ushort* lds, int row, int ks, int lane) {
    int slot = ((ks << 2) + (lane >> 4)) ^ (row & 7);
    return *(const short8*)&lds[row * 64 + slot * 8];
}
// fragment from [64][128] LDS tile (BK=128 bodies)
__device__ __forceinline__ short8 frag128(const ushort* lds, int row, int ks, int lane) {
    int slot = ((ks << 2) + (lane >> 4)) ^ (row & 7);
    return *(const short8*)&lds[row * 128 + slot * 8];
}

// stage one 64x128 panel (4 gloads/wave, 4 rows each), pre-swizzled source
__device__ __forceinline__ void stage128(
    const ushort* g, int row0, int k0, int w, int lane, ushort* lds)
{
    #pragma unroll
    for (int gg = 0; gg < 4; ++gg) {
        int row = row0 + w * 16 + gg * 4 + (lane >> 4);
        int slot = (lane & 15) ^ (row & 7);
        gload_lds16(g + (size_t)row * HID + k0 + slot * 8,
                    &lds[(w * 16 + gg * 4) * 128]);
    }
}

// ---- 64x64 tile, K=512 via 4 x BK=128 panels, depth-2 counted-vmcnt --------
__device__ __forceinline__ void gemm_bk128(
    ushort* A0, ushort* A1, ushort* B0, ushort* B1,
    int w, int lane, int wr, int wc,
    const ushort* Ag, int arow0, const ushort* Bg, int brow0,
    f32x4 acc[2][2])
{
    stage128(Ag, arow0, 0, w, lane, A0);
    stage128(Bg, brow0, 0, w, lane, B0);
    stage128(Ag, arow0, 128, w, lane, A1);
    stage128(Bg, brow0, 128, w, lane, B1);
    for (int t = 0; t < 4; ++t) {
        wait_vm((t < 3) ? 8 : 0);
        BARRIER();
        SCHED0();
        const ushort* Ab = (t & 1) ? A1 : A0;
        const ushort* Bb = (t & 1) ? B1 : B0;
        short8 af[2][4], bf[2][4];
        #pragma unroll
        for (int mi = 0; mi < 2; ++mi) {
            int r = wr * 32 + mi * 16 + (lane & 15);
            #pragma unroll
            for (int ks = 0; ks < 4; ++ks) af[mi][ks] = frag128(Ab, r, ks, lane);
        }
        #pragma unroll
        for (int ni = 0; ni < 2; ++ni) {
            int c = wc * 32 + ni * 16 + (lane & 15);
            #pragma unroll
            for (int ks = 0; ks < 4; ++ks) bf[ni][ks] = frag128(Bb, c, ks, lane);
        }
        #pragma unroll
        for (int ks = 0; ks < 4; ++ks)
            #pragma unroll
            for (int mi = 0; mi < 2; ++mi)
                #pragma unroll
                for (int ni = 0; ni < 2; ++ni)
                    acc[mi][ni] = MFMA(af[mi][ks], bf[ni][ks], acc[mi][ni]);
        SCHED0();
        BARRIER();
        if (t + 2 < 4) {
            stage128(Ag, arow0, (t + 2) * 128, w, lane, (t & 1) ? A1 : A0);
            stage128(Bg, brow0, (t + 2) * 128, w, lane, (t & 1) ? B1 : B0);
        }
    }
}

// ---- 64x64 tile, BK=64 x 8(+1 tail) panels, depth-2 counted-vmcnt ----------
__device__ __forceinline__ void gemm64_pipe(
    ushort* A0, ushort* A1, ushort* B0, ushort* B1,
    int w, int lane, int wr, int wc,
    const ushort* gA0, const ushort* gA1,
    const ushort* gB0, const ushort* gB1,
    const ushort* tA0, const ushort* tA1,
    const ushort* tB0, const ushort* tB1,
    int NT, bool tailToX, f32x4 acc[2][2], f32x4 accX[2][2])
{
    auto stage = [&](int b, int p) {
        ushort* A = b ? A1 : A0; ushort* B = b ? B1 : B0;
        if (p < 8) {
            gload_lds16(gA0 + (size_t)p * 64, &A[(w * 16) * 64]);
            gload_lds16(gA1 + (size_t)p * 64, &A[(w * 16 + 8) * 64]);
            gload_lds16(gB0 + (size_t)p * 64, &B[(w * 16) * 64]);
            gload_lds16(gB1 + (size_t)p * 64, &B[(w * 16 + 8) * 64]);
        } else {
            gload_lds16(tA0, &A[(w * 16) * 64]);
            gload_lds16(tA1, &A[(w * 16 + 8) * 64]);
            gload_lds16(tB0, &B[(w * 16) * 64]);
            gload_lds16(tB1, &B[(w * 16 + 8) * 64]);
        }
    };
    stage(0, 0);
    stage(1, 1);
    for (int t = 0; t < NT; ++t) {
        wait_vm((t + 1 < NT) ? 4 : 0);
        BARRIER();
        SCHED0();
        const ushort* Ab = (t & 1) ? A1 : A0;
        const ushort* Bb = (t & 1) ? B1 : B0;
        short8 af[2][2], bf[2][2];
        #pragma unroll
        for (int mi = 0; mi < 2; ++mi) {
            int r = wr * 32 + mi * 16 + (lane & 15);
            af[mi][0] = frag64(Ab, r, 0, lane);
            af[mi][1] = frag64(Ab, r, 1, lane);
        }
        #pragma unroll
        for (int ni = 0; ni < 2; ++ni) {
            int c = wc * 32 + ni * 16 + (lane & 15);
            bf[ni][0] = frag64(Bb, c, 0, lane);
            bf[ni][1] = frag64(Bb, c, 1, lane);
        }
        const bool toX = tailToX && (t == 8);
        #pragma unroll
        for (int ks = 0; ks < 2; ++ks)
            #pragma unroll
            for (int mi = 0; mi < 2; ++mi)
                #pragma unroll
                for (int ni = 0; ni < 2; ++ni) {
                    f32x4& a = toX ? accX[mi][ni] : acc[mi][ni];
                    a = MFMA(af[mi][ks], bf[ni][ks], a);
                }
        SCHED0();
        BARRIER();
        if (t + 2 < NT) stage(t & 1, t + 2);
    }
}

// ---------------- fuse1: ODE-A (bid<512) + q-head of prev event -------------
// mode 0: ode only (512); mode 1: ode + q (768); mode 2: q only (256)
__global__ __launch_bounds__(256) void fuse1(
    const ushort* __restrict__ hb, const ushort* __restrict__ W1,
    const float* __restrict__ b1, ushort* __restrict__ tbb,
    const ushort* __restrict__ hgb, const ushort* __restrict__ Wp1,
    const float* __restrict__ bp1, ushort* __restrict__ qb, int mode)
{
    __shared__ __align__(16) ushort smem[32768];
    ushort* A0 = smem;         ushort* A1 = smem + 8192;
    ushort* B0 = smem + 16384; ushort* B1 = smem + 24576;
    const int tid = threadIdx.x, lane = tid & 63, w = tid >> 6;
    const int wr = w >> 1, wc = w & 1;
    const int bid = blockIdx.x;

    bool isQ; int b;
    if (mode == 2)      { isQ = true;  b = bid; }
    else if (bid < 512) { isQ = false; b = bid; }
    else                { isQ = true;  b = bid - 512; }
    const ushort* A = isQ ? hgb : hb;
    const ushort* W = isQ ? Wp1 : W1;
    const float* bias = isQ ? bp1 : b1;
    const int r0 = (b >> 3) * 64, c0 = (b & 7) * 64;

    f32x4 acc[2][2] = {};
    gemm_bk128(A0, A1, B0, B1, w, lane, wr, wc, A, r0, W, c0, acc);

    #pragma unroll
    for (int mi = 0; mi < 2; ++mi)
        #pragma unroll
        for (int ni = 0; ni < 2; ++ni) {
            const int c = c0 + wc * 32 + ni * 16 + (lane & 15);
            const float bv = bias[c];
            #pragma unroll
            for (int ii = 0; ii < 4; ++ii) {
                const int r = r0 + wr * 32 + mi * 16 + ((lane >> 4) << 2) + ii;
                const size_t o = (size_t)r * HID + c;
                float v = acc[mi][ni][ii] + bv;
                if (!isQ) tbb[o] = f2bf(tanhf(v));
                else      qb[o]  = f2bf(fmaxf(v, 0.0f));
            }
        }
}

// ---------------- fuse2: ODE-B (bid<512) + p_loss of prev event -------------
// inv != nullptr -> also write hgb snapshot via inverse index (step 2 only)
// mode 0: ode only (512); mode 1: ode + p_loss (544); mode 2: p_loss only (32)
__global__ __launch_bounds__(256) void fuse2(
    const ushort* __restrict__ tbb, const ushort* __restrict__ W2,
    const float* __restrict__ b2, float* __restrict__ h, ushort* __restrict__ hb,
    const int* __restrict__ inv, ushort* __restrict__ hgb,
    const ushort* __restrict__ qb, const ushort* __restrict__ Wp2,
    const float* __restrict__ bp2, const float* __restrict__ Xp,
    const float* __restrict__ Mp, float* __restrict__ sums, int mode)
{
    __shared__ __align__(16) ushort smem[32768];
    const int tid = threadIdx.x, lane = tid & 63, w = tid >> 6;
    const int wr = w >> 1, wc = w & 1;
    const int bid = blockIdx.x;

    bool isP; int b;
    if (mode == 2)      { isP = true;  b = bid; }
    else if (bid < 512) { isP = false; b = bid; }
    else                { isP = true;  b = bid - 512; }

    if (!isP) {
        ushort* A0 = smem;         ushort* A1 = smem + 8192;
        ushort* B0 = smem + 16384; ushort* B1 = smem + 24576;
        const int r0 = (b >> 3) * 64, c0 = (b & 7) * 64;
        f32x4 acc[2][2] = {};
        gemm_bk128(A0, A1, B0, B1, w, lane, wr, wc, tbb, r0, W2, c0, acc);
        #pragma unroll
        for (int mi = 0; mi < 2; ++mi)
            #pragma unroll
            for (int ni = 0; ni < 2; ++ni) {
                const int c = c0 + wc * 32 + ni * 16 + (lane & 15);
                const float bv = b2[c];
                #pragma unroll
                for (int ii = 0; ii < 4; ++ii) {
                    const int r = r0 + wr * 32 + mi * 16 + ((lane >> 4) << 2) + ii;
                    const size_t o = (size_t)r * HID + c;
                    float nh = h[o] + DT_C * (acc[mi][ni][ii] + bv);
                    h[o] = nh;
                    ushort bv16 = f2bf(nh);
                    hb[o] = bv16;
                    if (inv) {
                        int iv = inv[r];
                        if (iv >= 0) hgb[(size_t)iv * HID + c] = bv16;
                    }
                }
            }
        return;
    }

    // ---- p_loss: p = q Wp2^T + bp2, fused NLL reduce (BK=64 body) ----
    ushort* A0 = smem;        ushort* A1 = smem + 4096;
    ushort* B0 = smem + 8192; ushort* B1 = smem + 16384;   // 128x64 each
    const int srow = lane >> 3, sg = ((lane & 7) ^ srow) << 3;
    const int r0t = b * 64;
    const int arow = w * 16 + srow;

    auto stage = [&](int bb, int k0) {
        ushort* A = bb ? A1 : A0; ushort* B = bb ? B1 : B0;
        gload_lds16(qb + (size_t)(r0t + arow) * HID + k0 + sg, &A[(w * 16) * 64]);
        gload_lds16(qb + (size_t)(r0t + arow + 8) * HID + k0 + sg, &A[(w * 16 + 8) * 64]);
        #pragma unroll
        for (int j = 0; j < 4; ++j) {
            int g = w * 4 + j;
            int rw = g * 8 + srow;
            gload_lds16(Wp2 + (size_t)rw * HID + k0 + (((lane & 7) ^ (rw & 7)) << 3),
                        &B[g * 8 * 64]);
        }
    };
    f32x4 acc[2][4] = {};
    stage(0, 0);
    stage(1, 64);
    for (int t = 0; t < 8; ++t) {
        wait_vm((t < 7) ? 6 : 0);
        BARRIER();
        SCHED0();
        const ushort* Ab = (t & 1) ? A1 : A0;
        const ushort* Bb = (t & 1) ? B1 : B0;
        short8 af[2][2], bf[4][2];
        #pragma unroll
        for (int mi = 0; mi < 2; ++mi) {
            int r = wr * 32 + mi * 16 + (lane & 15);
            af[mi][0] = frag64(Ab, r, 0, lane);
            af[mi][1] = frag64(Ab, r, 1, lane);
        }
        #pragma unroll
        for (int ni = 0; ni < 4; ++ni) {
            int c = wc * 64 + ni * 16 + (lane & 15);
            bf[ni][0] = frag64(Bb, c, 0, lane);
            bf[ni][1] = frag64(Bb, c, 1, lane);
        }
        #pragma unroll
        for (int ks = 0; ks < 2; ++ks)
            #pragma unroll
            for (int mi = 0; mi < 2; ++mi)
                #pragma unroll
                for (int ni = 0; ni < 4; ++ni)
                    acc[mi][ni] = MFMA(af[mi][ks], bf[ni][ks], acc[mi][ni]);
        SCHED0();
        BARRIER();
        if (t + 2 < 8) stage(t & 1, (t + 2) * 64);
    }

    float* Plds = (float*)smem;   // 64x128 f32 = 32KB
    #pragma unroll
    for (int mi = 0; mi < 2; ++mi)
        #pragma unroll
        for (int ni = 0; ni < 4; ++ni) {
            int c = wc * 64 + ni * 16 + (lane & 15);
            float bv = bp2[c];
            #pragma unroll
            for (int ii = 0; ii < 4; ++ii) {
                int r = wr * 32 + mi * 16 + ((lane >> 4) << 2) + ii;
                Plds[r * 128 + c] = acc[mi][ni][ii] + bv;
            }
        }
    __syncthreads();

    float local = 0.0f;
    for (int t = tid; t < 64 * 64; t += 256) {
        int r = t >> 6, jj = t & 63;
        float mean = Plds[r * 128 + jj];
        float lv   = Plds[r * 128 + 64 + jj];
        int g = r0t + r;
        float err = (Xp[(size_t)g * 64 + jj] - mean) * expf(-0.5f * lv);
        local += 0.5f * (err * err + lv + 2.0f * LOG_SQRT_2PI_C) * Mp[(size_t)g * 64 + jj];
    }
    #pragma unroll
    for (int o = 32; o > 0; o >>= 1) local += __shfl_down(local, o);
    if (lane == 0) atomicAdd(sums, local);
}

// ---------------- fuse5: rz (bid<512) + n-gate (bid>=512), A from hgb -------
// 768 blocks, 32KB LDS -> 4 blocks/CU. Writes rz / nh_ / nx_.
__global__ __launch_bounds__(256) void fuse5(
    const ushort* __restrict__ hgb, const ushort* __restrict__ Xbk,
    const ushort* __restrict__ Whh, const ushort* __restrict__ Wih,
    const float* __restrict__ bih, const float* __restrict__ bhh,
    float* __restrict__ rz, float* __restrict__ nh_, float* __restrict__ nx_)
{
    __shared__ __align__(16) ushort Alds[2][4096];
    __shared__ __align__(16) ushort Blds[2][4096];
    const int tid = threadIdx.x, lane = tid & 63, w = tid >> 6;
    const int wr = w >> 1, wc = w & 1;
    const int srow = lane >> 3, sg = ((lane & 7) ^ srow) << 3;
    const int bid = blockIdx.x;

    int r0t, c0;
    const ushort *Bh, *Bx;
    bool tailX;
    if (bid < 512) { r0t = (bid >> 4) * 64; c0 = (bid & 15) * 64; Bh = Whh; Bx = Wih; tailX = false; }
    else { int t3 = bid - 512; r0t = (t3 >> 3) * 64; c0 = (t3 & 7) * 64;
           Bh = Whh + (size_t)1024 * HID; Bx = Wih + (size_t)1024 * DIM; tailX = true; }

    const int ar0 = r0t + w * 16 + srow, ar1 = r0t + w * 16 + 8 + srow;
    f32x4 acc[2][2] = {}, accX[2][2] = {};
    gemm64_pipe(Alds[0], Alds[1], Blds[0], Blds[1], w, lane, wr, wc,
        hgb + (size_t)ar0 * HID + sg,
        hgb + (size_t)ar1 * HID + sg,
        Bh + (size_t)(c0 + w * 16 + srow) * HID + sg,
        Bh + (size_t)(c0 + w * 16 + 8 + srow) * HID + sg,
        Xbk + (size_t)ar0 * DIM + sg,
        Xbk + (size_t)ar1 * DIM + sg,
        Bx + (size_t)(c0 + w * 16 + srow) * DIM + sg,
        Bx + (size_t)(c0 + w * 16 + 8 + srow) * DIM + sg,
        9, tailX, acc, accX);

    #pragma unroll
    for (int mi = 0; mi < 2; ++mi)
        #pragma unroll
        for (int ni = 0; ni < 2; ++ni) {
            const int c = c0 + wc * 32 + ni * 16 + (lane & 15);
            #pragma unroll
            for (int ii = 0; ii < 4; ++ii) {
                const int iobs = r0t + wr * 32 + mi * 16 + ((lane >> 4) << 2) + ii;
                if (!tailX) {
                    rz[(size_t)iobs * 1024 + c] =
                        sigmoidf_(acc[mi][ni][ii] + bih[c] + bhh[c]);
                } else {
                    nh_[(size_t)iobs * HID + c] = acc[mi][ni][ii] + bhh[1024 + c];
                    nx_[(size_t)iobs * HID + c] = accX[mi][ni][ii] + bih[1024 + c];
                }
            }
        }
}

// ---------------- GRU combine + scatter (writes h AND hb) -------------------
__global__ __launch_bounds__(256) void combine_kernel(
    const float* __restrict__ rz, const float* __restrict__ nh_,
    const float* __restrict__ nx_, const int* __restrict__ idx,
    float* __restrict__ h, ushort* __restrict__ hb)
{
    int t = blockIdx.x * 256 + threadIdx.x;   // 65536 threads
    #pragma unroll
    for (int i = 0; i < 4; ++i) {
        int v = t + i * 65536;                // float4 id over 2048*512/4
        int row = v >> 7, j4 = (v & 127) << 2;
        float4 rr = *(const float4*)&rz[(size_t)row * 1024 + j4];
        float4 zz = *(const float4*)&rz[(size_t)row * 1024 + 512 + j4];
        float4 hn = *(const float4*)&nh_[(size_t)row * HID + j4];
        float4 xn = *(const float4*)&nx_[(size_t)row * HID + j4];
        size_t o = (size_t)idx[row] * HID + j4;
        float4 hv = *(const float4*)&h[o];
        float4 res; ushort4 ob;
        #define C1(c) { float n = tanhf(xn.c + rr.c * hn.c); \
                        res.c = (1.0f - zz.c) * n + zz.c * hv.c; ob.c = f2bf(res.c); }
        C1(x) C1(y) C1(z) C1(w)
        #undef C1
        *(float4*)&h[o] = res;
        *(ushort4*)&hb[o] = ob;
    }
}

__device__ __forceinline__ void block_atomic_sum(float v, float* acc) {
    __shared__ float red[4];
    #pragma unroll
    for (int off = 32; off > 0; off >>= 1) v += __shfl_down(v, off);
    int lane = threadIdx.x & 63, wid = threadIdx.x >> 6;
    if (lane == 0) red[wid] = v;
    __syncthreads();
    if (threadIdx.x == 0) atomicAdd(acc, red[0] + red[1] + red[2] + red[3]);
}

__global__ __launch_bounds__(256) void f2b4_kernel(
    const float* __restrict__ s, ushort* __restrict__ d, int n4)
{
    int t = blockIdx.x * 256 + threadIdx.x;
    if (t >= n4) return;
    float4 v = ((const float4*)s)[t];
    ushort4 o; o.x = f2bf(v.x); o.y = f2bf(v.y); o.z = f2bf(v.z); o.w = f2bf(v.w);
    ((ushort4*)d)[t] = o;
}

__global__ __launch_bounds__(256) void msum_kernel(
    const float* __restrict__ M, int n, float* __restrict__ m_acc)
{
    float v = 0.0f;
    for (int t = blockIdx.x * 256 + threadIdx.x; t < n; t += gridDim.x * 256)
        v += M[t];
    block_atomic_sum(v, m_acc);
}

__global__ __launch_bounds__(256) void inv_scatter(
    const int* __restrict__ bidx, int* __restrict__ inv)
{
    int t = blockIdx.x * 256 + threadIdx.x;   // over KEV*NPER
    if (t >= KEV * NPER) return;
    int e = t >> 11, i = t & (NPER - 1);
    inv[(size_t)e * BATCH + bidx[t]] = i;
}

__global__ void finalize_kernel(const float* __restrict__ sums, float* __restrict__ out) {
    if (threadIdx.x == 0) { out[0] = sums[0] / sums[1]; out[1] = 0.0f; }
}

extern "C" void kernel_launch(void* const* d_in, const int* in_sizes, int n_in,
                              void* d_out, int out_size, void* d_ws, size_t ws_size,
                              hipStream_t stream) {
    const float* X      = (const float*)d_in[3];
    const float* M      = (const float*)d_in[4];
    const int* batch_idx= (const int*)  d_in[5];
    const float* W_ode1 = (const float*)d_in[6];
    const float* b_ode1 = (const float*)d_in[7];
    const float* W_ode2 = (const float*)d_in[8];
    const float* b_ode2 = (const float*)d_in[9];
    const float* W_ih   = (const float*)d_in[10];
    const float* W_hh   = (const float*)d_in[11];
    const float* b_ih   = (const float*)d_in[12];
    const float* b_hh   = (const float*)d_in[13];
    const float* Wp1    = (const float*)d_in[14];
    const float* bp1    = (const float*)d_in[15];
    const float* Wp2    = (const float*)d_in[16];
    const float* bp2    = (const float*)d_in[17];
    float* out = (float*)d_out;

    float* ws    = (float*)d_ws;
    float* h     = ws;                                  // 4096*512
    float* rz    = h   + (size_t)BATCH * HID;           // 2048*1024
    float* nh_   = rz  + (size_t)NPER * 1024;           // 2048*512
    float* nx_   = nh_ + (size_t)NPER * HID;            // 2048*512
    float* sums  = nx_ + (size_t)NPER * HID;            // 16
    int*   inv   = (int*)(sums + 16);                   // 25*4096
    ushort* hb   = (ushort*)(inv + (size_t)KEV * BATCH);// 4096*512
    ushort* tbb  = hb  + (size_t)BATCH * HID;           // 4096*512
    ushort* qb   = tbb + (size_t)BATCH * HID;           // 2048*512
    ushort* hgb  = qb  + (size_t)NPER * HID;            // 2048*512
    ushort* Xb   = hgb + (size_t)NPER * HID;            // 25*2048*64
    ushort* W1b  = Xb  + (size_t)KEV * NPER * DIM;      // 512*512
    ushort* W2b  = W1b + (size_t)HID * HID;
    ushort* Wp1b = W2b + (size_t)HID * HID;
    ushort* Wp2b = Wp1b + (size_t)HID * HID;            // 128*512
    ushort* Wihb = Wp2b + (size_t)2 * DIM * HID;        // 1536*64
    ushort* Whhb = Wihb + (size_t)3 * HID * DIM;        // 1536*512

    hipMemsetAsync(h,    0, (size_t)BATCH * HID * sizeof(float), stream);
    hipMemsetAsync(hb,   0, (size_t)BATCH * HID * sizeof(ushort), stream);
    hipMemsetAsync(sums, 0, 2 * sizeof(float), stream);
    hipMemsetAsync(inv,  0xFF, (size_t)KEV * BATCH * sizeof(int), stream);

    dim3 blk(256);
    auto cvt = [&](const float* s, ushort* d, size_t n) {
        f2b4_kernel<<<dim3((unsigned)((n / 4 + 255) / 256)), blk, 0, stream>>>(s, d, (int)(n / 4));
    };
    cvt(W_ode1, W1b,  (size_t)HID * HID);
    cvt(W_ode2, W2b,  (size_t)HID * HID);
    cvt(Wp1,    Wp1b, (size_t)HID * HID);
    cvt(Wp2,    Wp2b, (size_t)2 * DIM * HID);
    cvt(W_ih,   Wihb, (size_t)3 * HID * DIM);
    cvt(W_hh,   Whhb, (size_t)3 * HID * HID);
    cvt(X,      Xb,   (size_t)KEV * NPER * DIM);

    msum_kernel<<<1024, blk, 0, stream>>>(M, KEV * NPER * DIM, sums + 1);
    inv_scatter<<<(KEV * NPER + 255) / 256, blk, 0, stream>>>(batch_idx, inv);

    for (int k = 0; k < KEV; ++k) {
        const ushort* Xbk = Xb + (size_t)k * NPER * DIM;
        const int*   idxk = batch_idx + (size_t)k * NPER;
        int* invk = inv + (size_t)k * BATCH;
        const float* Xp = X + (size_t)(k > 0 ? k - 1 : 0) * NPER * DIM;
        const float* Mp = M + (size_t)(k > 0 ? k - 1 : 0) * NPER * DIM;
        const int m1 = (k > 0) ? 1 : 0;

        // D1: ODE-A step1 (+ q of event k-1)
        fuse1<<<dim3(m1 ? 768 : 512), blk, 0, stream>>>(
            hb, W1b, b_ode1, tbb, hgb, Wp1b, bp1, qb, m1);
        // D2: ODE-B step1 (+ p_loss of event k-1); no snapshot
        fuse2<<<dim3(m1 ? 544 : 512), blk, 0, stream>>>(
            tbb, W2b, b_ode2, h, hb, nullptr, hgb,
            qb, Wp2b, bp2, Xp, Mp, sums, m1);
        // D3: ODE-A step2
        fuse1<<<dim3(512), blk, 0, stream>>>(
            hb, W1b, b_ode1, tbb, hgb, Wp1b, bp1, qb, 0);
        // D4: ODE-B step2 + hgb snapshot via inv
        fuse2<<<dim3(512), blk, 0, stream>>>(
            tbb, W2b, b_ode2, h, hb, invk, hgb,
            qb, Wp2b, bp2, Xp, Mp, sums, 0);
        // D5: GRU GEMMs (rz + n), A from hgb (coalesced), 4 blocks/CU
        fuse5<<<dim3(768), blk, 0, stream>>>(
            hgb, Xbk, Whhb, Wihb, b_ih, b_hh, rz, nh_, nx_);
        // D6: GRU combine + scatter (h and hb)
        combine_kernel<<<dim3(256), blk, 0, stream>>>(rz, nh_, nx_, idxk, h, hb);
    }

    // tail: head of final event
    {
        const float* Xp = X + (size_t)(KEV - 1) * NPER * DIM;
        const float* Mp = M + (size_t)(KEV - 1) * NPER * DIM;
        fuse1<<<dim3(256), blk, 0, stream>>>(
            hb, W1b, b_ode1, tbb, hgb, Wp1b, bp1, qb, 2);
        fuse2<<<dim3(32), blk, 0, stream>>>(
            tbb, W2b, b_ode2, h, hb, nullptr, hgb,
            qb, Wp2b, bp2, Xp, Mp, sums, 2);
    }

    finalize_kernel<<<1, 64, 0, stream>>>(sums, out);
}

// Round 16
// 1929.513 us; speedup vs baseline: 1.1882x; 1.1131x over previous
//
#include <hip/hip_runtime.h>
#include <cstdint>
#include <cstddef>

#define BATCH 4096
#define DIM 64
#define HID 512
#define NPER 2048
#define KEV 25
#define DT_C 0.01f
#define LOG_SQRT_2PI_C 0.9189385332046727f

typedef __attribute__((ext_vector_type(8))) short short8;
typedef __attribute__((ext_vector_type(4))) float f32x4;

#define MFMA(a, b, c) __builtin_amdgcn_mfma_f32_16x16x32_bf16(a, b, c, 0, 0, 0)
#define BARRIER() __builtin_amdgcn_s_barrier()
#define SCHED0()  __builtin_amdgcn_sched_barrier(0)

__device__ __forceinline__ ushort f2bf(float f) {
    uint32_t u = __float_as_uint(f);
    u += 0x7FFF + ((u >> 16) & 1);
    return (ushort)(u >> 16);
}
__device__ __forceinline__ float sigmoidf_(float x) { return 1.0f / (1.0f + expf(-x)); }

__device__ __forceinline__ void gload_lds16(const ushort* g, ushort* l) {
    __builtin_amdgcn_global_load_lds(
        (const __attribute__((address_space(1))) void*)g,
        (__attribute__((address_space(3))) void*)l, 16, 0, 0);
}
__device__ __forceinline__ void wait_vm(int n) {
    if (n == 8)      asm volatile("s_waitcnt vmcnt(8)" ::: "memory");
    else if (n == 6) asm volatile("s_waitcnt vmcnt(6)" ::: "memory");
    else if (n == 4) asm volatile("s_waitcnt vmcnt(4)" ::: "memory");
    else             asm volatile("s_waitcnt vmcnt(0)" ::: "memory");
}

// fragment from [rows][64] LDS tile, XOR-swizzled 8-elem slots (BK=64 bodies)
__device__ __forceinline__ short8 frag64(const ushort* lds, int row, int ks, int lane) {
    int slot = ((ks << 2) + (lane >> 4)) ^ (row & 7);
    return *(const short8*)&lds[row * 64 + slot * 8];
}
// fragment from [64][128] LDS tile (BK=128 bodies)
__device__ __forceinline__ short8 frag128(const ushort* lds, int row, int ks, int lane) {
    int slot = ((ks << 2) + (lane >> 4)) ^ (row & 7);
    return *(const short8*)&lds[row * 128 + slot * 8];
}

// stage one 64x128 panel (4 gloads/wave, 4 rows each), pre-swizzled source
__device__ __forceinline__ void stage128(
    const ushort* g, int row0, int k0, int w, int lane, ushort* lds)
{
    #pragma unroll
    for (int gg = 0; gg < 4; ++gg) {
        int row = row0 + w * 16 + gg * 4 + (lane >> 4);
        int slot = (lane & 15) ^ (row & 7);
        gload_lds16(g + (size_t)row * HID + k0 + slot * 8,
                    &lds[(w * 16 + gg * 4) * 128]);
    }
}

// ---- 64x64 tile, K=512 via 4 x BK=128 panels, depth-2 counted-vmcnt --------
__device__ __forceinline__ void gemm_bk128(
    ushort* A0, ushort* A1, ushort* B0, ushort* B1,
    int w, int lane, int wr, int wc,
    const ushort* Ag, int arow0, const ushort* Bg, int brow0,
    f32x4 acc[2][2])
{
    stage128(Ag, arow0, 0, w, lane, A0);
    stage128(Bg, brow0, 0, w, lane, B0);
    stage128(Ag, arow0, 128, w, lane, A1);
    stage128(Bg, brow0, 128, w, lane, B1);
    for (int t = 0; t < 4; ++t) {
        wait_vm((t < 3) ? 8 : 0);
        BARRIER();
        SCHED0();
        const ushort* Ab = (t & 1) ? A1 : A0;
        const ushort* Bb = (t & 1) ? B1 : B0;
        short8 af[2][4], bf[2][4];
        #pragma unroll
        for (int mi = 0; mi < 2; ++mi) {
            int r = wr * 32 + mi * 16 + (lane & 15);
            #pragma unroll
            for (int ks = 0; ks < 4; ++ks) af[mi][ks] = frag128(Ab, r, ks, lane);
        }
        #pragma unroll
        for (int ni = 0; ni < 2; ++ni) {
            int c = wc * 32 + ni * 16 + (lane & 15);
            #pragma unroll
            for (int ks = 0; ks < 4; ++ks) bf[ni][ks] = frag128(Bb, c, ks, lane);
        }
        #pragma unroll
        for (int ks = 0; ks < 4; ++ks)
            #pragma unroll
            for (int mi = 0; mi < 2; ++mi)
                #pragma unroll
                for (int ni = 0; ni < 2; ++ni)
                    acc[mi][ni] = MFMA(af[mi][ks], bf[ni][ks], acc[mi][ni]);
        SCHED0();
        BARRIER();
        if (t + 2 < 4) {
            stage128(Ag, arow0, (t + 2) * 128, w, lane, (t & 1) ? A1 : A0);
            stage128(Bg, brow0, (t + 2) * 128, w, lane, (t & 1) ? B1 : B0);
        }
    }
}

// ---------------- fuse1: ODE-A (bid<512) + q-head of prev event -------------
// mode 0: ode only (512); mode 1: ode + q (768); mode 2: q only (256)
__global__ __launch_bounds__(256) void fuse1(
    const ushort* __restrict__ hb, const ushort* __restrict__ W1,
    const float* __restrict__ b1, ushort* __restrict__ tbb,
    const ushort* __restrict__ hgb, const ushort* __restrict__ Wp1,
    const float* __restrict__ bp1, ushort* __restrict__ qb, int mode)
{
    __shared__ __align__(16) ushort smem[32768];
    ushort* A0 = smem;         ushort* A1 = smem + 8192;
    ushort* B0 = smem + 16384; ushort* B1 = smem + 24576;
    const int tid = threadIdx.x, lane = tid & 63, w = tid >> 6;
    const int wr = w >> 1, wc = w & 1;
    const int bid = blockIdx.x;

    bool isQ; int b;
    if (mode == 2)      { isQ = true;  b = bid; }
    else if (bid < 512) { isQ = false; b = bid; }
    else                { isQ = true;  b = bid - 512; }
    const ushort* A = isQ ? hgb : hb;
    const ushort* W = isQ ? Wp1 : W1;
    const float* bias = isQ ? bp1 : b1;
    const int r0 = (b >> 3) * 64, c0 = (b & 7) * 64;

    f32x4 acc[2][2] = {};
    gemm_bk128(A0, A1, B0, B1, w, lane, wr, wc, A, r0, W, c0, acc);

    #pragma unroll
    for (int mi = 0; mi < 2; ++mi)
        #pragma unroll
        for (int ni = 0; ni < 2; ++ni) {
            const int c = c0 + wc * 32 + ni * 16 + (lane & 15);
            const float bv = bias[c];
            #pragma unroll
            for (int ii = 0; ii < 4; ++ii) {
                const int r = r0 + wr * 32 + mi * 16 + ((lane >> 4) << 2) + ii;
                const size_t o = (size_t)r * HID + c;
                float v = acc[mi][ni][ii] + bv;
                if (!isQ) tbb[o] = f2bf(tanhf(v));
                else      qb[o]  = f2bf(fmaxf(v, 0.0f));
            }
        }
}

// ---------------- fuse2: ODE-B (bid<512) + p_loss of prev event -------------
// inv != nullptr -> also write hgb snapshot via inverse index (step 2 only)
// mode 0: ode only (512); mode 1: ode + p_loss (544); mode 2: p_loss only (32)
__global__ __launch_bounds__(256) void fuse2(
    const ushort* __restrict__ tbb, const ushort* __restrict__ W2,
    const float* __restrict__ b2, float* __restrict__ h, ushort* __restrict__ hb,
    const int* __restrict__ inv, ushort* __restrict__ hgb,
    const ushort* __restrict__ qb, const ushort* __restrict__ Wp2,
    const float* __restrict__ bp2, const float* __restrict__ Xp,
    const float* __restrict__ Mp, float* __restrict__ sums, int mode)
{
    __shared__ __align__(16) ushort smem[32768];
    const int tid = threadIdx.x, lane = tid & 63, w = tid >> 6;
    const int wr = w >> 1, wc = w & 1;
    const int bid = blockIdx.x;

    bool isP; int b;
    if (mode == 2)      { isP = true;  b = bid; }
    else if (bid < 512) { isP = false; b = bid; }
    else                { isP = true;  b = bid - 512; }

    if (!isP) {
        ushort* A0 = smem;         ushort* A1 = smem + 8192;
        ushort* B0 = smem + 16384; ushort* B1 = smem + 24576;
        const int r0 = (b >> 3) * 64, c0 = (b & 7) * 64;
        f32x4 acc[2][2] = {};
        gemm_bk128(A0, A1, B0, B1, w, lane, wr, wc, tbb, r0, W2, c0, acc);
        #pragma unroll
        for (int mi = 0; mi < 2; ++mi)
            #pragma unroll
            for (int ni = 0; ni < 2; ++ni) {
                const int c = c0 + wc * 32 + ni * 16 + (lane & 15);
                const float bv = b2[c];
                #pragma unroll
                for (int ii = 0; ii < 4; ++ii) {
                    const int r = r0 + wr * 32 + mi * 16 + ((lane >> 4) << 2) + ii;
                    const size_t o = (size_t)r * HID + c;
                    float nh = h[o] + DT_C * (acc[mi][ni][ii] + bv);
                    h[o] = nh;
                    ushort bv16 = f2bf(nh);
                    hb[o] = bv16;
                    if (inv) {
                        int iv = inv[r];
                        if (iv >= 0) hgb[(size_t)iv * HID + c] = bv16;
                    }
                }
            }
        return;
    }

    // ---- p_loss: p = q Wp2^T + bp2, fused NLL reduce (BK=64 body) ----
    ushort* A0 = smem;        ushort* A1 = smem + 4096;
    ushort* B0 = smem + 8192; ushort* B1 = smem + 16384;   // 128x64 each
    const int srow = lane >> 3, sg = ((lane & 7) ^ srow) << 3;
    const int r0t = b * 64;
    const int arow = w * 16 + srow;

    auto stage = [&](int bb, int k0) {
        ushort* A = bb ? A1 : A0; ushort* B = bb ? B1 : B0;
        gload_lds16(qb + (size_t)(r0t + arow) * HID + k0 + sg, &A[(w * 16) * 64]);
        gload_lds16(qb + (size_t)(r0t + arow + 8) * HID + k0 + sg, &A[(w * 16 + 8) * 64]);
        #pragma unroll
        for (int j = 0; j < 4; ++j) {
            int g = w * 4 + j;
            int rw = g * 8 + srow;
            gload_lds16(Wp2 + (size_t)rw * HID + k0 + (((lane & 7) ^ (rw & 7)) << 3),
                        &B[g * 8 * 64]);
        }
    };
    f32x4 acc[2][4] = {};
    stage(0, 0);
    stage(1, 64);
    for (int t = 0; t < 8; ++t) {
        wait_vm((t < 7) ? 6 : 0);
        BARRIER();
        SCHED0();
        const ushort* Ab = (t & 1) ? A1 : A0;
        const ushort* Bb = (t & 1) ? B1 : B0;
        short8 af[2][2], bf[4][2];
        #pragma unroll
        for (int mi = 0; mi < 2; ++mi) {
            int r = wr * 32 + mi * 16 + (lane & 15);
            af[mi][0] = frag64(Ab, r, 0, lane);
            af[mi][1] = frag64(Ab, r, 1, lane);
        }
        #pragma unroll
        for (int ni = 0; ni < 4; ++ni) {
            int c = wc * 64 + ni * 16 + (lane & 15);
            bf[ni][0] = frag64(Bb, c, 0, lane);
            bf[ni][1] = frag64(Bb, c, 1, lane);
        }
        #pragma unroll
        for (int ks = 0; ks < 2; ++ks)
            #pragma unroll
            for (int mi = 0; mi < 2; ++mi)
                #pragma unroll
                for (int ni = 0; ni < 4; ++ni)
                    acc[mi][ni] = MFMA(af[mi][ks], bf[ni][ks], acc[mi][ni]);
        SCHED0();
        BARRIER();
        if (t + 2 < 8) stage(t & 1, (t + 2) * 64);
    }

    float* Plds = (float*)smem;   // 64x128 f32 = 32KB
    #pragma unroll
    for (int mi = 0; mi < 2; ++mi)
        #pragma unroll
        for (int ni = 0; ni < 4; ++ni) {
            int c = wc * 64 + ni * 16 + (lane & 15);
            float bv = bp2[c];
            #pragma unroll
            for (int ii = 0; ii < 4; ++ii) {
                int r = wr * 32 + mi * 16 + ((lane >> 4) << 2) + ii;
                Plds[r * 128 + c] = acc[mi][ni][ii] + bv;
            }
        }
    __syncthreads();

    float local = 0.0f;
    for (int t = tid; t < 64 * 64; t += 256) {
        int r = t >> 6, jj = t & 63;
        float mean = Plds[r * 128 + jj];
        float lv   = Plds[r * 128 + 64 + jj];
        int g = r0t + r;
        float err = (Xp[(size_t)g * 64 + jj] - mean) * expf(-0.5f * lv);
        local += 0.5f * (err * err + lv + 2.0f * LOG_SQRT_2PI_C) * Mp[(size_t)g * 64 + jj];
    }
    #pragma unroll
    for (int o = 32; o > 0; o >>= 1) local += __shfl_down(local, o);
    if (lane == 0) atomicAdd(sums, local);
}

// ---------------- gru_all: r,z,n GEMMs + combine + scatter, one block/tile --
// grid 256 = 32 row-tiles x 8 col-tiles. A read from hgb (stable snapshot).
__global__ __launch_bounds__(256) void gru_all(
    const ushort* __restrict__ hgb, const ushort* __restrict__ Xbk,
    const int* __restrict__ idx,
    const ushort* __restrict__ Whh, const ushort* __restrict__ Wih,
    const float* __restrict__ bih, const float* __restrict__ bhh,
    float* __restrict__ h, ushort* __restrict__ hb)
{
    __shared__ __align__(16) ushort smem[32768];   // A:2x4096 @0, B:2x3x4096 @8192
    const int tid = threadIdx.x, lane = tid & 63, w = tid >> 6;
    const int wr = w >> 1, wc = w & 1;
    const int srow = lane >> 3, sg = ((lane & 7) ^ srow) << 3;
    const int bid = blockIdx.x;
    const int r0t = (bid >> 3) * 64, c0 = (bid & 7) * 64;

    auto stage = [&](int b, int p) {
        ushort* A = smem + b * 4096;
        if (p < 8) {
            gload_lds16(hgb + (size_t)(r0t + w * 16 + srow) * HID + p * 64 + sg,
                        &A[(w * 16) * 64]);
            gload_lds16(hgb + (size_t)(r0t + w * 16 + 8 + srow) * HID + p * 64 + sg,
                        &A[(w * 16 + 8) * 64]);
            #pragma unroll
            for (int g = 0; g < 3; ++g) {
                ushort* B = smem + 8192 + (b * 3 + g) * 4096;
                gload_lds16(Whh + (size_t)(g * 512 + c0 + w * 16 + srow) * HID + p * 64 + sg,
                            &B[(w * 16) * 64]);
                gload_lds16(Whh + (size_t)(g * 512 + c0 + w * 16 + 8 + srow) * HID + p * 64 + sg,
                            &B[(w * 16 + 8) * 64]);
            }
        } else {
            gload_lds16(Xbk + (size_t)(r0t + w * 16 + srow) * DIM + sg, &A[(w * 16) * 64]);
            gload_lds16(Xbk + (size_t)(r0t + w * 16 + 8 + srow) * DIM + sg, &A[(w * 16 + 8) * 64]);
            #pragma unroll
            for (int g = 0; g < 3; ++g) {
                ushort* B = smem + 8192 + (b * 3 + g) * 4096;
                gload_lds16(Wih + (size_t)(g * 512 + c0 + w * 16 + srow) * DIM + sg,
                            &B[(w * 16) * 64]);
                gload_lds16(Wih + (size_t)(g * 512 + c0 + w * 16 + 8 + srow) * DIM + sg,
                            &B[(w * 16 + 8) * 64]);
            }
        }
    };

    f32x4 aR[2][2] = {}, aZ[2][2] = {}, aNh[2][2] = {}, aNx[2][2] = {};
    stage(0, 0);
    stage(1, 1);
    for (int t = 0; t < 8; ++t) {
        wait_vm(8);
        BARRIER();
        SCHED0();
        const ushort* Ab = smem + (t & 1) * 4096;
        short8 af[2][2];
        #pragma unroll
        for (int mi = 0; mi < 2; ++mi) {
            int r = wr * 32 + mi * 16 + (lane & 15);
            af[mi][0] = frag64(Ab, r, 0, lane);
            af[mi][1] = frag64(Ab, r, 1, lane);
        }
        #pragma unroll
        for (int g = 0; g < 3; ++g) {
            const ushort* Bb = smem + 8192 + ((t & 1) * 3 + g) * 4096;
            short8 bf[2][2];
            #pragma unroll
            for (int ni = 0; ni < 2; ++ni) {
                int c = wc * 32 + ni * 16 + (lane & 15);
                bf[ni][0] = frag64(Bb, c, 0, lane);
                bf[ni][1] = frag64(Bb, c, 1, lane);
            }
            #pragma unroll
            for (int ks = 0; ks < 2; ++ks)
                #pragma unroll
                for (int mi = 0; mi < 2; ++mi)
                    #pragma unroll
                    for (int ni = 0; ni < 2; ++ni) {
                        f32x4& a = (g == 0) ? aR[mi][ni] : (g == 1) ? aZ[mi][ni] : aNh[mi][ni];
                        a = MFMA(af[mi][ks], bf[ni][ks], a);
                    }
        }
        SCHED0();
        BARRIER();
        if (t + 2 < 9) stage(t & 1, t + 2);
    }
    // ---- peeled tail (panel 8): A=Xbk, B=Wih; n-gate x-part into aNx ----
    {
        wait_vm(0);
        BARRIER();
        SCHED0();
        const ushort* Ab = smem;   // buf 0 holds panel 8
        short8 af[2][2];
        #pragma unroll
        for (int mi = 0; mi < 2; ++mi) {
            int r = wr * 32 + mi * 16 + (lane & 15);
            af[mi][0] = frag64(Ab, r, 0, lane);
            af[mi][1] = frag64(Ab, r, 1, lane);
        }
        #pragma unroll
        for (int g = 0; g < 3; ++g) {
            const ushort* Bb = smem + 8192 + g * 4096;
            short8 bf[2][2];
            #pragma unroll
            for (int ni = 0; ni < 2; ++ni) {
                int c = wc * 32 + ni * 16 + (lane & 15);
                bf[ni][0] = frag64(Bb, c, 0, lane);
                bf[ni][1] = frag64(Bb, c, 1, lane);
            }
            #pragma unroll
            for (int ks = 0; ks < 2; ++ks)
                #pragma unroll
                for (int mi = 0; mi < 2; ++mi)
                    #pragma unroll
                    for (int ni = 0; ni < 2; ++ni) {
                        f32x4& a = (g == 0) ? aR[mi][ni] : (g == 1) ? aZ[mi][ni] : aNx[mi][ni];
                        a = MFMA(af[mi][ks], bf[ni][ks], a);
                    }
        }
    }

    // ---- epilogue: full GRU combine + scatter into h (fp32) and hb ----
    #pragma unroll
    for (int mi = 0; mi < 2; ++mi)
        #pragma unroll
        for (int ni = 0; ni < 2; ++ni) {
            const int c = c0 + wc * 32 + ni * 16 + (lane & 15);
            const float bR = bih[c] + bhh[c];
            const float bZ = bih[512 + c] + bhh[512 + c];
            const float bNx = bih[1024 + c], bNh = bhh[1024 + c];
            #pragma unroll
            for (int ii = 0; ii < 4; ++ii) {
                const int iobs = r0t + wr * 32 + mi * 16 + ((lane >> 4) << 2) + ii;
                const int gr = idx[iobs];
                float r = sigmoidf_(aR[mi][ni][ii] + bR);
                float z = sigmoidf_(aZ[mi][ni][ii] + bZ);
                float n = tanhf(aNx[mi][ni][ii] + bNx + r * (aNh[mi][ni][ii] + bNh));
                const size_t o = (size_t)gr * HID + c;
                float nh = (1.0f - z) * n + z * h[o];
                h[o] = nh;
                hb[o] = f2bf(nh);
            }
        }
}

__device__ __forceinline__ void block_atomic_sum(float v, float* acc) {
    __shared__ float red[4];
    #pragma unroll
    for (int off = 32; off > 0; off >>= 1) v += __shfl_down(v, off);
    int lane = threadIdx.x & 63, wid = threadIdx.x >> 6;
    if (lane == 0) red[wid] = v;
    __syncthreads();
    if (threadIdx.x == 0) atomicAdd(acc, red[0] + red[1] + red[2] + red[3]);
}

__global__ __launch_bounds__(256) void f2b4_kernel(
    const float* __restrict__ s, ushort* __restrict__ d, int n4)
{
    int t = blockIdx.x * 256 + threadIdx.x;
    if (t >= n4) return;
    float4 v = ((const float4*)s)[t];
    ushort4 o; o.x = f2bf(v.x); o.y = f2bf(v.y); o.z = f2bf(v.z); o.w = f2bf(v.w);
    ((ushort4*)d)[t] = o;
}

__global__ __launch_bounds__(256) void msum_kernel(
    const float* __restrict__ M, int n, float* __restrict__ m_acc)
{
    float v = 0.0f;
    for (int t = blockIdx.x * 256 + threadIdx.x; t < n; t += gridDim.x * 256)
        v += M[t];
    block_atomic_sum(v, m_acc);
}

__global__ __launch_bounds__(256) void inv_scatter(
    const int* __restrict__ bidx, int* __restrict__ inv)
{
    int t = blockIdx.x * 256 + threadIdx.x;   // over KEV*NPER
    if (t >= KEV * NPER) return;
    int e = t >> 11, i = t & (NPER - 1);
    inv[(size_t)e * BATCH + bidx[t]] = i;
}

__global__ void finalize_kernel(const float* __restrict__ sums, float* __restrict__ out) {
    if (threadIdx.x == 0) { out[0] = sums[0] / sums[1]; out[1] = 0.0f; }
}

extern "C" void kernel_launch(void* const* d_in, const int* in_sizes, int n_in,
                              void* d_out, int out_size, void* d_ws, size_t ws_size,
                              hipStream_t stream) {
    const float* X      = (const float*)d_in[3];
    const float* M      = (const float*)d_in[4];
    const int* batch_idx= (const int*)  d_in[5];
    const float* W_ode1 = (const float*)d_in[6];
    const float* b_ode1 = (const float*)d_in[7];
    const float* W_ode2 = (const float*)d_in[8];
    const float* b_ode2 = (const float*)d_in[9];
    const float* W_ih   = (const float*)d_in[10];
    const float* W_hh   = (const float*)d_in[11];
    const float* b_ih   = (const float*)d_in[12];
    const float* b_hh   = (const float*)d_in[13];
    const float* Wp1    = (const float*)d_in[14];
    const float* bp1    = (const float*)d_in[15];
    const float* Wp2    = (const float*)d_in[16];
    const float* bp2    = (const float*)d_in[17];
    float* out = (float*)d_out;

    float* ws    = (float*)d_ws;
    float* h     = ws;                                  // 4096*512
    float* sums  = h + (size_t)BATCH * HID;             // 16
    int*   inv   = (int*)(sums + 16);                   // 25*4096
    ushort* hb   = (ushort*)(inv + (size_t)KEV * BATCH);// 4096*512
    ushort* tbb  = hb  + (size_t)BATCH * HID;           // 4096*512
    ushort* qb   = tbb + (size_t)BATCH * HID;           // 2048*512
    ushort* hgb  = qb  + (size_t)NPER * HID;            // 2048*512
    ushort* Xb   = hgb + (size_t)NPER * HID;            // 25*2048*64
    ushort* W1b  = Xb  + (size_t)KEV * NPER * DIM;      // 512*512
    ushort* W2b  = W1b + (size_t)HID * HID;
    ushort* Wp1b = W2b + (size_t)HID * HID;
    ushort* Wp2b = Wp1b + (size_t)HID * HID;            // 128*512
    ushort* Wihb = Wp2b + (size_t)2 * DIM * HID;        // 1536*64
    ushort* Whhb = Wihb + (size_t)3 * HID * DIM;        // 1536*512

    hipMemsetAsync(h,    0, (size_t)BATCH * HID * sizeof(float), stream);
    hipMemsetAsync(hb,   0, (size_t)BATCH * HID * sizeof(ushort), stream);
    hipMemsetAsync(sums, 0, 2 * sizeof(float), stream);
    hipMemsetAsync(inv,  0xFF, (size_t)KEV * BATCH * sizeof(int), stream);

    dim3 blk(256);
    auto cvt = [&](const float* s, ushort* d, size_t n) {
        f2b4_kernel<<<dim3((unsigned)((n / 4 + 255) / 256)), blk, 0, stream>>>(s, d, (int)(n / 4));
    };
    cvt(W_ode1, W1b,  (size_t)HID * HID);
    cvt(W_ode2, W2b,  (size_t)HID * HID);
    cvt(Wp1,    Wp1b, (size_t)HID * HID);
    cvt(Wp2,    Wp2b, (size_t)2 * DIM * HID);
    cvt(W_ih,   Wihb, (size_t)3 * HID * DIM);
    cvt(W_hh,   Whhb, (size_t)3 * HID * HID);
    cvt(X,      Xb,   (size_t)KEV * NPER * DIM);

    msum_kernel<<<1024, blk, 0, stream>>>(M, KEV * NPER * DIM, sums + 1);
    inv_scatter<<<(KEV * NPER + 255) / 256, blk, 0, stream>>>(batch_idx, inv);

    for (int k = 0; k < KEV; ++k) {
        const ushort* Xbk = Xb + (size_t)k * NPER * DIM;
        const int*   idxk = batch_idx + (size_t)k * NPER;
        int* invk = inv + (size_t)k * BATCH;
        const float* Xp = X + (size_t)(k > 0 ? k - 1 : 0) * NPER * DIM;
        const float* Mp = M + (size_t)(k > 0 ? k - 1 : 0) * NPER * DIM;
        const int m1 = (k > 0) ? 1 : 0;

        // D1: ODE-A step1 (+ q of event k-1)
        fuse1<<<dim3(m1 ? 768 : 512), blk, 0, stream>>>(
            hb, W1b, b_ode1, tbb, hgb, Wp1b, bp1, qb, m1);
        // D2: ODE-B step1 (+ p_loss of event k-1); no snapshot
        fuse2<<<dim3(m1 ? 544 : 512), blk, 0, stream>>>(
            tbb, W2b, b_ode2, h, hb, nullptr, hgb,
            qb, Wp2b, bp2, Xp, Mp, sums, m1);
        // D3: ODE-A step2
        fuse1<<<dim3(512), blk, 0, stream>>>(
            hb, W1b, b_ode1, tbb, hgb, Wp1b, bp1, qb, 0);
        // D4: ODE-B step2 + hgb snapshot via inv
        fuse2<<<dim3(512), blk, 0, stream>>>(
            tbb, W2b, b_ode2, h, hb, invk, hgb,
            qb, Wp2b, bp2, Xp, Mp, sums, 0);
        // D5: GRU fused (r,z,n GEMMs + combine + scatter)
        gru_all<<<dim3(256), blk, 0, stream>>>(
            hgb, Xbk, idxk, Whhb, Wihb, b_ih, b_hh, h, hb);
    }

    // tail: head of final event
    {
        const float* Xp = X + (size_t)(KEV - 1) * NPER * DIM;
        const float* Mp = M + (size_t)(KEV - 1) * NPER * DIM;
        fuse1<<<dim3(256), blk, 0, stream>>>(
            hb, W1b, b_ode1, tbb, hgb, Wp1b, bp1, qb, 2);
        fuse2<<<dim3(32), blk, 0, stream>>>(
            tbb, W2b, b_ode2, h, hb, nullptr, hgb,
            qb, Wp2b, bp2, Xp, Mp, sums, 2);
    }

    finalize_kernel<<<1, 64, 0, stream>>>(sums, out);
}